// Round 5
// baseline (2159.121 us; speedup 1.0000x reference)
//
#include <hip/hip_runtime.h>
#include <hip/hip_bf16.h>

#define N_NODES 100000
#define N_EDGES 1200000
#define N_GRAPHS 512
#define HID 64
#define IN_DIM 16
#define EPS 1e-5f

#define NB_BUCKETS 391   // ceil(N_NODES / BUCKET_SPAN)
#define BUCKET_SPAN 256  // dst >> 8
#define REGION 4096      // per-bucket region capacity (avg real fill ~3069)
#define BIN_TILE 4096    // edges per bin block
#define CSR_LEN (N_EDGES + N_NODES)  // self-loops folded in
#define NREP 64          // stats replicas (atomic de-contention)
#define STATS_BLKS 64    // extra blocks appended to bin grid for input-BN stats

#define MEGA_BLOCKS 1280 // 5 blocks/CU x 256 CUs: co-resident by construction
#define MEGA_WAVES (MEGA_BLOCKS * 4)

typedef _Float16 half4 __attribute__((ext_vector_type(4)));
typedef _Float16 half8 __attribute__((ext_vector_type(8)));

// ------------- bin (edge bucketing) + input-BN stats (merged independent work) -------------

__global__ void bin_stats_kernel(const int* __restrict__ ei, int* __restrict__ bucketCnt,
                                 int* __restrict__ regions, const float* __restrict__ x,
                                 float* __restrict__ sums, float* __restrict__ sumsq,
                                 _Float16* __restrict__ hwBuf, int nbBin) {
    __shared__ int hist[NB_BUCKETS], basem[NB_BUCKETS], cur[NB_BUCKETS];
    __shared__ float ls[16], lq[16];
    int t = threadIdx.x;

    if (blockIdx.x >= nbBin) {
        // ---- stats path: float4 loads; residue class (i&3) fixed per thread ----
        const int sblk = blockIdx.x - nbBin;
        if (sblk == 0 && t < 8)  // zero f16 dummy gather row of hwBuf (beyond regions alias)
            ((float4*)(hwBuf + (size_t)N_NODES * HID))[t] = make_float4(0.f, 0.f, 0.f, 0.f);
        if (t < 16) { ls[t] = 0.f; lq[t] = 0.f; }
        __syncthreads();
        const float4* x4 = (const float4*)x;
        const int total4 = N_NODES * IN_DIM / 4;  // 400000
        float s0 = 0.f, s1 = 0.f, s2 = 0.f, s3 = 0.f;
        float q0 = 0.f, q1 = 0.f, q2 = 0.f, q3 = 0.f;
        int i = sblk * 256 + t;
        const int fb = (i & 3) * 4;  // stride 16384 ≡ 0 mod 4 → invariant
        for (; i < total4; i += STATS_BLKS * 256) {
            float4 v = x4[i];
            s0 += v.x; q0 += v.x * v.x;
            s1 += v.y; q1 += v.y * v.y;
            s2 += v.z; q2 += v.z * v.z;
            s3 += v.w; q3 += v.w * v.w;
        }
        atomicAdd(&ls[fb + 0], s0); atomicAdd(&lq[fb + 0], q0);
        atomicAdd(&ls[fb + 1], s1); atomicAdd(&lq[fb + 1], q1);
        atomicAdd(&ls[fb + 2], s2); atomicAdd(&lq[fb + 2], q2);
        atomicAdd(&ls[fb + 3], s3); atomicAdd(&lq[fb + 3], q3);
        __syncthreads();
        if (t < 16) { atomicAdd(&sums[t], ls[t]); atomicAdd(&sumsq[t], lq[t]); }
        return;
    }

    // ---- bin path ----
    for (int i = t; i < NB_BUCKETS; i += 256) { hist[i] = 0; cur[i] = 0; }
    __syncthreads();
    const int4* ei4s = (const int4*)ei;
    const int4* ei4d = (const int4*)(ei + N_EDGES);
    int srcs[16], dsts[16];
#pragma unroll
    for (int i = 0; i < 4; i++) {
        int idx4 = blockIdx.x * (BIN_TILE / 4) + t + i * 256;
        if (idx4 * 4 < N_EDGES) {
            int4 s4 = ei4s[idx4];
            int4 d4 = ei4d[idx4];
            srcs[i * 4 + 0] = s4.x; dsts[i * 4 + 0] = d4.x;
            srcs[i * 4 + 1] = s4.y; dsts[i * 4 + 1] = d4.y;
            srcs[i * 4 + 2] = s4.z; dsts[i * 4 + 2] = d4.z;
            srcs[i * 4 + 3] = s4.w; dsts[i * 4 + 3] = d4.w;
            atomicAdd(&hist[d4.x >> 8], 1);
            atomicAdd(&hist[d4.y >> 8], 1);
            atomicAdd(&hist[d4.z >> 8], 1);
            atomicAdd(&hist[d4.w >> 8], 1);
        } else {
            dsts[i * 4 + 0] = -1; dsts[i * 4 + 1] = -1;
            dsts[i * 4 + 2] = -1; dsts[i * 4 + 3] = -1;
        }
    }
    __syncthreads();
    for (int i = t; i < NB_BUCKETS; i += 256) {
        int h = hist[i];
        basem[i] = h ? atomicAdd(&bucketCnt[i], h) : 0;
    }
    __syncthreads();
#pragma unroll
    for (int i = 0; i < 16; i++) {
        if (dsts[i] >= 0) {
            int b = dsts[i] >> 8;
            int pos = basem[b] + atomicAdd(&cur[b], 1);
            if (pos < REGION)
                regions[b * REGION + pos] = srcs[i] | ((dsts[i] & 255) << 17);
        }
    }
}

// ------------- CSR build (wave-shfl scans: 4 barriers) -------------

__global__ void build_kernel(const int* __restrict__ regions, const int* __restrict__ bucketCnt,
                             int* __restrict__ csrOff, int* __restrict__ csrSrc,
                             float* __restrict__ dis) {
    __shared__ int deg[256], cur[256];
    __shared__ int slice[REGION + 256];
    __shared__ int wred1[4], wred2[4];
    int b = blockIdx.x, t = threadIdx.x;
    const int laneid = t & 63;
    const int w = t >> 6;

    {
        int s = 0;
        for (int i = t; i < NB_BUCKETS; i += 256)
            if (i < b) s += min(bucketCnt[i], REGION);
#pragma unroll
        for (int d = 1; d < 64; d <<= 1) s += __shfl_xor(s, d, 64);
        if (laneid == 0) wred1[w] = s;
    }
    int cnt = min(bucketCnt[b], REGION);
    int nbase = b * BUCKET_SPAN;
    int n = nbase + t;
    bool valid = (n < N_NODES);
    deg[t] = valid ? 1 : 0;  // self loop
    __syncthreads();
    const int bb = wred1[0] + wred1[1] + wred1[2] + wred1[3] + b * BUCKET_SPAN;

    for (int i = t; i < cnt; i += 256) {
        int rec = regions[b * REGION + i];
        atomicAdd(&deg[rec >> 17], 1);
    }
    __syncthreads();
    int d = deg[t];

    int v = d;
#pragma unroll
    for (int sh = 1; sh < 64; sh <<= 1) {
        int u = __shfl_up(v, sh, 64);
        if (laneid >= sh) v += u;
    }
    if (laneid == 63) wred2[w] = v;
    __syncthreads();
    int wpre = 0;
#pragma unroll
    for (int ww = 0; ww < 4; ww++)
        if (ww < w) wpre += wred2[ww];
    const int tot = wred2[0] + wred2[1] + wred2[2] + wred2[3];
    int excl = v + wpre - d;

    if (valid) {
        csrOff[n] = bb + excl;
        dis[n] = rsqrtf((float)d);
    }
    if (b == 0 && t == 0) csrOff[N_NODES] = CSR_LEN;
    cur[t] = excl;
    __syncthreads();
    if (valid) {
        int pos = atomicAdd(&cur[t], 1);
        slice[pos] = n;
    }
    for (int i = t; i < cnt; i += 256) {
        int rec = regions[b * REGION + i];
        int pos = atomicAdd(&cur[rec >> 17], 1);
        slice[pos] = rec & 0x1FFFF;
    }
    __syncthreads();
    for (int i = t; i < tot; i += 256) csrSrc[bb + i] = slice[i];
}

// ---------------- BN coefficient helpers ----------------

__device__ __forceinline__ void bn_coef(const float* sums, const float* sumsq,
                                        const float* gamma, const float* beta, int k,
                                        float& sc, float& sh) {
    const float invn = 1.0f / (float)N_NODES;
    float m = sums[k] * invn;
    float var = sumsq[k] * invn - m * m;
    float rs = rsqrtf(var + EPS);
    sc = gamma[k] * rs;
    sh = beta[k] - m * sc;
}

__device__ __forceinline__ void bn_coef_rep(const float* rep, const float* gamma,
                                            const float* beta, int k, float& sc, float& sh) {
    float S = 0.f, Q = 0.f;
    for (int r = 0; r < NREP; r++) { S += rep[r * 128 + k]; Q += rep[r * 128 + 64 + k]; }
    const float invn = 1.0f / (float)N_NODES;
    float m = S * invn;
    float var = Q * invn - m * m;
    float rs = rsqrtf(var + EPS);
    sc = gamma[k] * rs;
    sh = beta[k] - m * sc;
}

// ---------------- device-scope grid barrier (co-resident persistent grid) ----------------
// gbar layout per id: [id*64] counter, [id*64+32] flag (128 B apart; zeroed by memset)

__device__ __forceinline__ void gridbar(int* gbar, int id) {
    __syncthreads();
    if (threadIdx.x == 0) {
        __threadfence();  // release: drain + L2 writeback (device scope)
        int* cnt = &gbar[id * 64];
        int* flg = &gbar[id * 64 + 32];
        int v = __hip_atomic_fetch_add(cnt, 1, __ATOMIC_ACQ_REL, __HIP_MEMORY_SCOPE_AGENT);
        if (v == MEGA_BLOCKS - 1) {
            __hip_atomic_store(flg, 1, __ATOMIC_RELEASE, __HIP_MEMORY_SCOPE_AGENT);
        } else {
            while (!__hip_atomic_load(flg, __ATOMIC_ACQUIRE, __HIP_MEMORY_SCOPE_AGENT))
                __builtin_amdgcn_s_sleep(32);
        }
        __threadfence();  // acquire: invalidate stale cache lines
    }
    __syncthreads();
}

// ---------------- mega kernel phase helpers (SM = 4352-float shared scratch) ----------------

// GEMM 64x64, 64-row tiles, W streamed from L1; BN(rep)+relu in, dis-scale out.
__device__ void gemm_phase(const _Float16* __restrict__ hin, const float* __restrict__ W,
                           const float* __restrict__ rep, const float* __restrict__ gamma,
                           const float* __restrict__ beta, const float* __restrict__ dis,
                           _Float16* __restrict__ hout, float* SM) {
    const int t = threadIdx.x;
    float* hs = SM;               // [64][66]
    float* scb = SM + 4224;
    float* shb = SM + 4288;
    if (t < 64) bn_coef_rep(rep, gamma, beta, t, scb[t], shb[t]);
    __syncthreads();
    const int fg = t & 15;
    const int rg = t >> 4;
    const float4* W4 = (const float4*)W;
    const half4* hin4 = (const half4*)hin;
    half4* hout4 = (half4*)hout;
    const int nvb = (N_NODES + 63) / 64;  // 1563
    for (int vb = blockIdx.x; vb < nvb; vb += MEGA_BLOCKS) {
        int base = vb * 64;
        for (int i = t; i < 64 * 16; i += 256) {
            int r = i >> 4, c = i & 15;
            int n = base + r;
            float4 v = make_float4(0.f, 0.f, 0.f, 0.f);
            if (n < N_NODES) {
                half4 h = hin4[n * 16 + c];
                v.x = fmaxf((float)h.x * scb[c * 4 + 0] + shb[c * 4 + 0], 0.f);
                v.y = fmaxf((float)h.y * scb[c * 4 + 1] + shb[c * 4 + 1], 0.f);
                v.z = fmaxf((float)h.z * scb[c * 4 + 2] + shb[c * 4 + 2], 0.f);
                v.w = fmaxf((float)h.w * scb[c * 4 + 3] + shb[c * 4 + 3], 0.f);
            }
            hs[r * 66 + c * 4 + 0] = v.x;
            hs[r * 66 + c * 4 + 1] = v.y;
            hs[r * 66 + c * 4 + 2] = v.z;
            hs[r * 66 + c * 4 + 3] = v.w;
        }
        __syncthreads();
        float4 acc[4];
#pragma unroll
        for (int r = 0; r < 4; r++) acc[r] = make_float4(0.f, 0.f, 0.f, 0.f);
        for (int k = 0; k < HID; k += 2) {
            float4 wk0 = W4[k * 16 + fg];
            float4 wk1 = W4[(k + 1) * 16 + fg];
#pragma unroll
            for (int r = 0; r < 4; r++) {
                float2 h2 = *(const float2*)&hs[(rg * 4 + r) * 66 + k];
                acc[r].x += h2.x * wk0.x + h2.y * wk1.x;
                acc[r].y += h2.x * wk0.y + h2.y * wk1.y;
                acc[r].z += h2.x * wk0.z + h2.y * wk1.z;
                acc[r].w += h2.x * wk0.w + h2.y * wk1.w;
            }
        }
#pragma unroll
        for (int r = 0; r < 4; r++) {
            int n = base + rg * 4 + r;
            if (n < N_NODES) {
                float dsc = dis[n];
                half4 o;
                o.x = (_Float16)(acc[r].x * dsc);
                o.y = (_Float16)(acc[r].y * dsc);
                o.z = (_Float16)(acc[r].z * dsc);
                o.w = (_Float16)(acc[r].w * dsc);
                hout4[n * 16 + fg] = o;
            }
        }
        __syncthreads();  // protect hs before next tile
    }
}

// Aggregation 64-dim: 2 nodes/wave (4 slots x 8 half8-cols), 2-deep prefetch.
__device__ void agg64_phase(const half8* __restrict__ hwh, const int* __restrict__ csrOff,
                            const int* __restrict__ csrSrc, const float* __restrict__ dis,
                            const float* __restrict__ bias, half8* __restrict__ y8,
                            float* __restrict__ statsRep, float* SM) {
    const int lane = threadIdx.x & 63;
    const int wid = threadIdx.x >> 6;
    const int g = lane >> 5;
    const int s = lane & 31;
    const int c = s & 7;
    const int o = s >> 3;
    const int wave = blockIdx.x * 4 + wid;

    const float4 bv0 = ((const float4*)bias)[c * 2];
    const float4 bv1 = ((const float4*)bias)[c * 2 + 1];
    float sa[8], qa[8];
#pragma unroll
    for (int j = 0; j < 8; j++) { sa[j] = 0.f; qa[j] = 0.f; }

    for (int n0 = wave * 2; n0 < N_NODES; n0 += MEGA_WAVES * 2) {
        int n = n0 + g;
        bool vn = (n < N_NODES);
        int beg = 0, end = 0;
        if (vn) { beg = csrOff[n]; end = csrOff[n + 1]; }
        float acc[8];
#pragma unroll
        for (int j = 0; j < 8; j++) acc[j] = 0.f;
        int e = beg + o;
        int i0 = (e < end) ? csrSrc[e] : N_NODES;
        int i1 = (e + 4 < end) ? csrSrc[e + 4] : N_NODES;
        while (e < end) {
            int j0 = i0, j1 = i1;
            e += 8;
            i0 = (e < end) ? csrSrc[e] : N_NODES;
            i1 = (e + 4 < end) ? csrSrc[e + 4] : N_NODES;
            half8 h0 = hwh[(size_t)j0 * 8 + c];
            half8 h1 = hwh[(size_t)j1 * 8 + c];
#pragma unroll
            for (int j = 0; j < 8; j++) acc[j] += (float)h0[j] + (float)h1[j];
        }
#pragma unroll
        for (int j = 0; j < 8; j++) {
            acc[j] += __shfl_xor(acc[j], 8, 64);
            acc[j] += __shfl_xor(acc[j], 16, 64);
        }
        if (o == 0 && vn) {
            float d = dis[n];
            float val[8];
            val[0] = acc[0] * d + bv0.x; val[1] = acc[1] * d + bv0.y;
            val[2] = acc[2] * d + bv0.z; val[3] = acc[3] * d + bv0.w;
            val[4] = acc[4] * d + bv1.x; val[5] = acc[5] * d + bv1.y;
            val[6] = acc[6] * d + bv1.z; val[7] = acc[7] * d + bv1.w;
            half8 ov;
#pragma unroll
            for (int j = 0; j < 8; j++) ov[j] = (_Float16)val[j];
            y8[(size_t)n * 8 + c] = ov;
#pragma unroll
            for (int j = 0; j < 8; j++) { sa[j] += val[j]; qa[j] += val[j] * val[j]; }
        }
    }
#pragma unroll
    for (int j = 0; j < 8; j++) {
        sa[j] += __shfl_xor(sa[j], 32, 64);
        qa[j] += __shfl_xor(qa[j], 32, 64);
    }
    float* ls = SM;          // [4][64]
    float* lq = SM + 256;    // [4][64]
    ls[wid * 64 + lane] = 0.f;
    lq[wid * 64 + lane] = 0.f;
    if (lane < 8) {
#pragma unroll
        for (int j = 0; j < 8; j++) {
            ls[wid * 64 + lane * 8 + j] = sa[j];
            lq[wid * 64 + lane * 8 + j] = qa[j];
        }
    }
    __syncthreads();
    if (wid == 0) {
        float S = ls[lane] + ls[64 + lane] + ls[128 + lane] + ls[192 + lane];
        float Q = lq[lane] + lq[64 + lane] + lq[128 + lane] + lq[192 + lane];
        float* rep = statsRep + (blockIdx.x & (NREP - 1)) * 128;
        atomicAdd(&rep[lane], S);
        atomicAdd(&rep[64 + lane], Q);
    }
    __syncthreads();  // release SM
}

// ---------------- the mega kernel: premsg .. head, 7 grid barriers ----------------

__global__ __launch_bounds__(256, 5) void mega_kernel(
    const float* __restrict__ x, const float* __restrict__ s0,
    const float* __restrict__ bn_in_g, const float* __restrict__ bn_in_b,
    const float* __restrict__ dis, const int* __restrict__ csrOff,
    const int* __restrict__ csrSrc, _Float16* __restrict__ msgBuf,
    const float* __restrict__ W0, const float* __restrict__ b0,
    _Float16* __restrict__ yBuf, _Float16* __restrict__ hwBuf,
    float* __restrict__ statsRep,
    const float* __restrict__ W1, const float* __restrict__ b1,
    const float* __restrict__ g0, const float* __restrict__ be0,
    const float* __restrict__ W2, const float* __restrict__ b2,
    const float* __restrict__ g1, const float* __restrict__ be1,
    const float* __restrict__ g2, const float* __restrict__ be2,
    const int* __restrict__ batch, float* __restrict__ pool, float* __restrict__ cnt,
    const float* __restrict__ Wc1, const float* __restrict__ bc1,
    const float* __restrict__ Wc2, const float* __restrict__ bc2,
    float* __restrict__ out, int* __restrict__ gbar) {
    __shared__ float SM[4352];
    const int t = threadIdx.x;
    float* rep1 = statsRep;
    float* rep2 = statsRep + NREP * 128;
    float* rep3 = statsRep + 2 * NREP * 128;

    // ---- P0: premsg — m[n] = BN(x[n]) * dis[n] (f16), zero dummy row ----
    {
        float* sc16 = SM;
        float* sh16 = SM + 16;
        if (t < 16) bn_coef(s0, s0 + 64, bn_in_g, bn_in_b, t, sc16[t], sh16[t]);
        __syncthreads();
        half4* m4 = (half4*)msgBuf;
        for (int idx = blockIdx.x * 256 + t; idx < (N_NODES + 1) * 4;
             idx += MEGA_BLOCKS * 256) {
            int n = idx >> 2, c = idx & 3;
            half4 o;
            o.x = (_Float16)0.f; o.y = (_Float16)0.f; o.z = (_Float16)0.f; o.w = (_Float16)0.f;
            if (n < N_NODES) {
                float4 h = ((const float4*)x)[idx];
                float d = dis[n];
                o.x = (_Float16)((h.x * sc16[c * 4 + 0] + sh16[c * 4 + 0]) * d);
                o.y = (_Float16)((h.y * sc16[c * 4 + 1] + sh16[c * 4 + 1]) * d);
                o.z = (_Float16)((h.z * sc16[c * 4 + 2] + sh16[c * 4 + 2]) * d);
                o.w = (_Float16)((h.w * sc16[c * 4 + 3] + sh16[c * 4 + 3]) * d);
            }
            m4[idx] = o;
        }
    }
    gridbar(gbar, 0);

    // ---- P1: fused 16-dim aggregate + W0 GEMM -> yBuf, rep1 ----
    {
        const int lane = t & 63;
        const int wid = t >> 6;
        const int g = lane >> 4;
        const int s = lane & 15;
        const int fl = s & 3;
        const int q = s >> 2;
        const int wave = blockIdx.x * 4 + wid;
        const half4* m4 = (const half4*)msgBuf;

        float wreg[16][4];
#pragma unroll
        for (int k = 0; k < 16; k++) {
#pragma unroll
            for (int j = 0; j < 4; j++) wreg[k][j] = W0[k * HID + s + 16 * j];
        }
        float bj[4];
#pragma unroll
        for (int j = 0; j < 4; j++) bj[j] = b0[s + 16 * j];
        float sv[4] = {0.f, 0.f, 0.f, 0.f}, qv[4] = {0.f, 0.f, 0.f, 0.f};

        for (int n0 = wave * 4; n0 < N_NODES; n0 += MEGA_WAVES * 4) {
            int n = n0 + g;
            bool vn = (n < N_NODES);
            int beg = 0, end = 0;
            if (vn) { beg = csrOff[n]; end = csrOff[n + 1]; }
            float4 acc = make_float4(0.f, 0.f, 0.f, 0.f);
            int e = beg + q;
            int i0 = (e < end) ? csrSrc[e] : N_NODES;
            int i1 = (e + 4 < end) ? csrSrc[e + 4] : N_NODES;
            while (e < end) {
                int j0 = i0, j1 = i1;
                e += 8;
                i0 = (e < end) ? csrSrc[e] : N_NODES;
                i1 = (e + 4 < end) ? csrSrc[e + 4] : N_NODES;
                half4 v0 = m4[(size_t)j0 * 4 + fl];
                half4 v1 = m4[(size_t)j1 * 4 + fl];
                acc.x += (float)v0.x + (float)v1.x;
                acc.y += (float)v0.y + (float)v1.y;
                acc.z += (float)v0.z + (float)v1.z;
                acc.w += (float)v0.w + (float)v1.w;
            }
            acc.x += __shfl_xor(acc.x, 4, 64);  acc.y += __shfl_xor(acc.y, 4, 64);
            acc.z += __shfl_xor(acc.z, 4, 64);  acc.w += __shfl_xor(acc.w, 4, 64);
            acc.x += __shfl_xor(acc.x, 8, 64);  acc.y += __shfl_xor(acc.y, 8, 64);
            acc.z += __shfl_xor(acc.z, 8, 64);  acc.w += __shfl_xor(acc.w, 8, 64);
            float d = vn ? dis[n] : 0.f;
            acc.x *= d; acc.y *= d; acc.z *= d; acc.w *= d;
            float yv0 = bj[0], yv1 = bj[1], yv2 = bj[2], yv3 = bj[3];
            const int gbase = lane & 48;
#pragma unroll
            for (int k = 0; k < 16; k++) {
                float comp = ((k & 3) == 0) ? acc.x : ((k & 3) == 1) ? acc.y
                            : ((k & 3) == 2) ? acc.z : acc.w;
                float a = __shfl(comp, gbase + (k >> 2), 64);
                yv0 += a * wreg[k][0];
                yv1 += a * wreg[k][1];
                yv2 += a * wreg[k][2];
                yv3 += a * wreg[k][3];
            }
            if (vn) {
                _Float16* yr = yBuf + (size_t)n * HID;
                yr[s] = (_Float16)yv0; yr[s + 16] = (_Float16)yv1;
                yr[s + 32] = (_Float16)yv2; yr[s + 48] = (_Float16)yv3;
                sv[0] += yv0; qv[0] += yv0 * yv0;
                sv[1] += yv1; qv[1] += yv1 * yv1;
                sv[2] += yv2; qv[2] += yv2 * yv2;
                sv[3] += yv3; qv[3] += yv3 * yv3;
            }
        }
#pragma unroll
        for (int j = 0; j < 4; j++) {
            sv[j] += __shfl_xor(sv[j], 16, 64); sv[j] += __shfl_xor(sv[j], 32, 64);
            qv[j] += __shfl_xor(qv[j], 16, 64); qv[j] += __shfl_xor(qv[j], 32, 64);
        }
        float* ls = SM;        // [4][64]
        float* lq = SM + 256;  // [4][64]
        if (g == 0) {
#pragma unroll
            for (int j = 0; j < 4; j++) {
                ls[wid * 64 + s + 16 * j] = sv[j];
                lq[wid * 64 + s + 16 * j] = qv[j];
            }
        }
        __syncthreads();
        if (wid == 0) {
            float S = ls[lane] + ls[64 + lane] + ls[128 + lane] + ls[192 + lane];
            float Q = lq[lane] + lq[64 + lane] + lq[128 + lane] + lq[192 + lane];
            float* rep = rep1 + (blockIdx.x & (NREP - 1)) * 128;
            atomicAdd(&rep[lane], S);
            atomicAdd(&rep[64 + lane], Q);
        }
    }
    gridbar(gbar, 1);

    // ---- P2: gemm layer1 (yBuf -> hwBuf) ----
    gemm_phase(yBuf, W1, rep1, g0, be0, dis, hwBuf, SM);
    gridbar(gbar, 2);

    // ---- P3: aggregate layer1 (hwBuf -> yBuf, rep2) ----
    agg64_phase((const half8*)hwBuf, csrOff, csrSrc, dis, b1, (half8*)yBuf, rep2, SM);
    gridbar(gbar, 3);

    // ---- P4: gemm layer2 (yBuf -> hwBuf) ----
    gemm_phase(yBuf, W2, rep2, g1, be1, dis, hwBuf, SM);
    gridbar(gbar, 4);

    // ---- P5: aggregate layer2 (hwBuf -> yBuf, rep3) ----
    agg64_phase((const half8*)hwBuf, csrOff, csrSrc, dis, b2, (half8*)yBuf, rep3, SM);
    gridbar(gbar, 5);

    // ---- P6: pool (BN(rep3)+relu fused) ----
    {
        float* scs = SM;
        float* shs = SM + 64;
        if (t < 64) bn_coef_rep(rep3, g2, be2, t, scs[t], shs[t]);
        __syncthreads();
        const int f = t & 63;
        const int nl = t >> 6;
        float sc = scs[f], sh = shs[f];
        const int nbPool = (N_NODES + 255) / 256;
        for (int vb = blockIdx.x; vb < nbPool; vb += MEGA_BLOCKS) {
            int base = vb * 256;
            int endn = min(base + 256, N_NODES);
            int g_cur = -1;
            float acc = 0.f, c_acc = 0.f;
            for (int n = base + nl; n < endn; n += 4) {
                int gg = batch[n];
                float v = fmaxf((float)yBuf[(size_t)n * HID + f] * sc + sh, 0.f);
                if (gg != g_cur) {
                    if (g_cur >= 0) {
                        atomicAdd(&pool[g_cur * HID + f], acc);
                        if (f == 0) atomicAdd(&cnt[g_cur], c_acc);
                    }
                    g_cur = gg;
                    acc = 0.f;
                    c_acc = 0.f;
                }
                acc += v;
                c_acc += 1.f;
            }
            if (g_cur >= 0) {
                atomicAdd(&pool[g_cur * HID + f], acc);
                if (f == 0) atomicAdd(&cnt[g_cur], c_acc);
            }
        }
        __syncthreads();
    }
    gridbar(gbar, 6);

    // ---- P7: head ----
    if (blockIdx.x < N_GRAPHS) {
        int g = blockIdx.x;
        float* p = SM;
        float* z = SM + 64;
        if (t < 64) {
            float c = fmaxf(cnt[g], 1.0f);
            p[t] = pool[g * HID + t] / c;
        }
        __syncthreads();
        if (t < 64) {
            float acc = bc1[t];
            for (int k = 0; k < 64; k++) acc += p[k] * Wc1[k * 64 + t];
            z[t] = fmaxf(acc, 0.f);
        }
        __syncthreads();
        if (t < 2) {
            float o = bc2[t];
            for (int k = 0; k < 64; k++) o += z[k] * Wc2[k * 2 + t];
            out[g * 2 + t] = o;
        }
    }
}

// ---------------- launch ----------------

extern "C" void kernel_launch(void* const* d_in, const int* in_sizes, int n_in,
                              void* d_out, int out_size, void* d_ws, size_t ws_size,
                              hipStream_t stream) {
    const float* x      = (const float*)d_in[0];
    const int*   ei     = (const int*)d_in[1];
    const int*   batch  = (const int*)d_in[2];
    const float* bn_in_g = (const float*)d_in[3];
    const float* bn_in_b = (const float*)d_in[4];
    const float* W0 = (const float*)d_in[5];
    const float* b0 = (const float*)d_in[6];
    const float* g0 = (const float*)d_in[7];
    const float* be0 = (const float*)d_in[8];
    const float* W1 = (const float*)d_in[9];
    const float* b1 = (const float*)d_in[10];
    const float* g1 = (const float*)d_in[11];
    const float* be1 = (const float*)d_in[12];
    const float* W2 = (const float*)d_in[13];
    const float* b2 = (const float*)d_in[14];
    const float* g2 = (const float*)d_in[15];
    const float* be2 = (const float*)d_in[16];
    const float* Wc1 = (const float*)d_in[17];
    const float* bc1 = (const float*)d_in[18];
    const float* Wc2 = (const float*)d_in[19];
    const float* bc2 = (const float*)d_in[20];
    float* out = (float*)d_out;

    char* w = (char*)d_ws;
    size_t off = 0;
    auto take = [&](size_t bytes) {
        size_t r = off;
        off += (bytes + 255) & ~(size_t)255;
        return r;
    };
    // ---- zero region (one memset) ----
    float* stats    = (float*)(w + take(256 * 4));             // s0: [sums 64][sumsq 64]
    float* statsRep = (float*)(w + take(3 * NREP * 128 * 4));  // replicated accumulators
    float* pool     = (float*)(w + take((size_t)N_GRAPHS * HID * 4));
    float* cnt      = (float*)(w + take((size_t)N_GRAPHS * 4));
    int* bucketCnt  = (int*)(w + take((size_t)NB_BUCKETS * 4));
    int* gbar       = (int*)(w + take(7 * 64 * 4));            // 7 barriers x 256 B
    size_t zero_end = off;
    // ---- rest ----
    float* dis    = (float*)(w + take((size_t)N_NODES * 4));
    int* csrOff   = (int*)(w + take((size_t)(N_NODES + 1) * 4));
    int* csrSrc   = (int*)(w + take((size_t)(CSR_LEN + 64) * 4));
    _Float16* hwBuf = (_Float16*)(w + take((size_t)(N_NODES + 1) * HID * 2));  // f16 msgs +dummy
    _Float16* yBuf  = (_Float16*)(w + take((size_t)N_NODES * HID * 2));        // f16 activations
    _Float16* msgBuf = (_Float16*)(w + take((size_t)(N_NODES + 1) * IN_DIM * 2));  // f16 16-dim
    int* regions  = (int*)hwBuf;   // alias: consumed by build_kernel before gemm writes
    (void)ws_size; (void)n_in; (void)in_sizes; (void)out_size;

    hipMemsetAsync(w, 0, zero_end, stream);

    const int nbBin = (N_EDGES + BIN_TILE - 1) / BIN_TILE;  // 293
    float* s0 = stats;

    // CSR build (bucketed; self-loops folded in) + input BN stats
    bin_stats_kernel<<<nbBin + STATS_BLKS, 256, 0, stream>>>(ei, bucketCnt, regions, x, s0,
                                                             s0 + 64, hwBuf, nbBin);
    build_kernel<<<NB_BUCKETS, 256, 0, stream>>>(regions, bucketCnt, csrOff, csrSrc, dis);

    // everything else: one persistent kernel, 7 device-scope grid barriers
    mega_kernel<<<MEGA_BLOCKS, 256, 0, stream>>>(
        x, s0, bn_in_g, bn_in_b, dis, csrOff, csrSrc, msgBuf, W0, b0, yBuf, hwBuf, statsRep,
        W1, b1, g0, be0, W2, b2, g1, be1, g2, be2, batch, pool, cnt, Wc1, bc1, Wc2, bc2,
        out, gbar);
}

// Round 6
// 546.040 us; speedup vs baseline: 3.9541x; 3.9541x over previous
//
#include <hip/hip_runtime.h>
#include <hip/hip_bf16.h>

#define N_NODES 100000
#define N_EDGES 1200000
#define N_GRAPHS 512
#define HID 64
#define IN_DIM 16
#define EPS 1e-5f

#define NB_BUCKETS 391   // ceil(N_NODES / BUCKET_SPAN)
#define BUCKET_SPAN 256  // dst >> 8
#define REGION 4096      // per-bucket region capacity (avg real fill ~3069)
#define BIN_TILE 4096    // edges per bin block
#define CSR_LEN (N_EDGES + N_NODES)  // self-loops folded in
#define NREP 64          // stats replicas (atomic de-contention)
#define STATS_BLKS 64    // extra blocks appended to bin grid for input-BN stats

#define MEGA_BLOCKS 1024 // 4 blocks/CU x 256 CUs: co-resident; 128-VGPR budget (no spill)
#define MEGA_WAVES (MEGA_BLOCKS * 4)

typedef _Float16 half4 __attribute__((ext_vector_type(4)));
typedef _Float16 half8 __attribute__((ext_vector_type(8)));

// ------------- bin (edge bucketing) + input-BN stats (merged independent work) -------------

__global__ void bin_stats_kernel(const int* __restrict__ ei, int* __restrict__ bucketCnt,
                                 int* __restrict__ regions, const float* __restrict__ x,
                                 float* __restrict__ sums, float* __restrict__ sumsq,
                                 _Float16* __restrict__ hwBuf, int nbBin) {
    __shared__ int hist[NB_BUCKETS], basem[NB_BUCKETS], cur[NB_BUCKETS];
    __shared__ float ls[16], lq[16];
    int t = threadIdx.x;

    if (blockIdx.x >= nbBin) {
        // ---- stats path: float4 loads; residue class (i&3) fixed per thread ----
        const int sblk = blockIdx.x - nbBin;
        if (sblk == 0 && t < 8)  // zero f16 dummy gather row of hwBuf (beyond regions alias)
            ((float4*)(hwBuf + (size_t)N_NODES * HID))[t] = make_float4(0.f, 0.f, 0.f, 0.f);
        if (t < 16) { ls[t] = 0.f; lq[t] = 0.f; }
        __syncthreads();
        const float4* x4 = (const float4*)x;
        const int total4 = N_NODES * IN_DIM / 4;  // 400000
        float s0 = 0.f, s1 = 0.f, s2 = 0.f, s3 = 0.f;
        float q0 = 0.f, q1 = 0.f, q2 = 0.f, q3 = 0.f;
        int i = sblk * 256 + t;
        const int fb = (i & 3) * 4;  // stride 16384 ≡ 0 mod 4 → invariant
        for (; i < total4; i += STATS_BLKS * 256) {
            float4 v = x4[i];
            s0 += v.x; q0 += v.x * v.x;
            s1 += v.y; q1 += v.y * v.y;
            s2 += v.z; q2 += v.z * v.z;
            s3 += v.w; q3 += v.w * v.w;
        }
        atomicAdd(&ls[fb + 0], s0); atomicAdd(&lq[fb + 0], q0);
        atomicAdd(&ls[fb + 1], s1); atomicAdd(&lq[fb + 1], q1);
        atomicAdd(&ls[fb + 2], s2); atomicAdd(&lq[fb + 2], q2);
        atomicAdd(&ls[fb + 3], s3); atomicAdd(&lq[fb + 3], q3);
        __syncthreads();
        if (t < 16) { atomicAdd(&sums[t], ls[t]); atomicAdd(&sumsq[t], lq[t]); }
        return;
    }

    // ---- bin path ----
    for (int i = t; i < NB_BUCKETS; i += 256) { hist[i] = 0; cur[i] = 0; }
    __syncthreads();
    const int4* ei4s = (const int4*)ei;
    const int4* ei4d = (const int4*)(ei + N_EDGES);
    int srcs[16], dsts[16];
#pragma unroll
    for (int i = 0; i < 4; i++) {
        int idx4 = blockIdx.x * (BIN_TILE / 4) + t + i * 256;
        if (idx4 * 4 < N_EDGES) {
            int4 s4 = ei4s[idx4];
            int4 d4 = ei4d[idx4];
            srcs[i * 4 + 0] = s4.x; dsts[i * 4 + 0] = d4.x;
            srcs[i * 4 + 1] = s4.y; dsts[i * 4 + 1] = d4.y;
            srcs[i * 4 + 2] = s4.z; dsts[i * 4 + 2] = d4.z;
            srcs[i * 4 + 3] = s4.w; dsts[i * 4 + 3] = d4.w;
            atomicAdd(&hist[d4.x >> 8], 1);
            atomicAdd(&hist[d4.y >> 8], 1);
            atomicAdd(&hist[d4.z >> 8], 1);
            atomicAdd(&hist[d4.w >> 8], 1);
        } else {
            dsts[i * 4 + 0] = -1; dsts[i * 4 + 1] = -1;
            dsts[i * 4 + 2] = -1; dsts[i * 4 + 3] = -1;
        }
    }
    __syncthreads();
    for (int i = t; i < NB_BUCKETS; i += 256) {
        int h = hist[i];
        basem[i] = h ? atomicAdd(&bucketCnt[i], h) : 0;
    }
    __syncthreads();
#pragma unroll
    for (int i = 0; i < 16; i++) {
        if (dsts[i] >= 0) {
            int b = dsts[i] >> 8;
            int pos = basem[b] + atomicAdd(&cur[b], 1);
            if (pos < REGION)
                regions[b * REGION + pos] = srcs[i] | ((dsts[i] & 255) << 17);
        }
    }
}

// ------------- CSR build (wave-shfl scans) + fused premsg tail -------------

__global__ void build_kernel(const int* __restrict__ regions, const int* __restrict__ bucketCnt,
                             int* __restrict__ csrOff, int* __restrict__ csrSrc,
                             float* __restrict__ dis, const float* __restrict__ x,
                             const float* __restrict__ sums, const float* __restrict__ sumsq,
                             const float* __restrict__ gamma, const float* __restrict__ beta,
                             half4* __restrict__ m4) {
    __shared__ int deg[256], cur[256];
    __shared__ int slice[REGION + 256];
    __shared__ int wred1[4], wred2[4];
    __shared__ float sc16[16], sh16[16];
    int b = blockIdx.x, t = threadIdx.x;
    const int laneid = t & 63;
    const int w = t >> 6;

    if (t < 16) {  // BN coefs for premsg tail (stats final: prior dispatch)
        const float invn = 1.0f / (float)N_NODES;
        float m = sums[t] * invn;
        float var = sumsq[t] * invn - m * m;
        float rs = rsqrtf(var + EPS);
        sc16[t] = gamma[t] * rs;
        sh16[t] = beta[t] - m * sc16[t];
    }
    {
        int s = 0;
        for (int i = t; i < NB_BUCKETS; i += 256)
            if (i < b) s += min(bucketCnt[i], REGION);
#pragma unroll
        for (int d = 1; d < 64; d <<= 1) s += __shfl_xor(s, d, 64);
        if (laneid == 0) wred1[w] = s;
    }
    int cnt = min(bucketCnt[b], REGION);
    int nbase = b * BUCKET_SPAN;
    int n = nbase + t;
    bool valid = (n < N_NODES);
    deg[t] = valid ? 1 : 0;  // self loop
    __syncthreads();
    const int bb = wred1[0] + wred1[1] + wred1[2] + wred1[3] + b * BUCKET_SPAN;

    for (int i = t; i < cnt; i += 256) {
        int rec = regions[b * REGION + i];
        atomicAdd(&deg[rec >> 17], 1);
    }
    __syncthreads();
    int d = deg[t];

    int v = d;
#pragma unroll
    for (int sh = 1; sh < 64; sh <<= 1) {
        int u = __shfl_up(v, sh, 64);
        if (laneid >= sh) v += u;
    }
    if (laneid == 63) wred2[w] = v;
    __syncthreads();
    int wpre = 0;
#pragma unroll
    for (int ww = 0; ww < 4; ww++)
        if (ww < w) wpre += wred2[ww];
    const int tot = wred2[0] + wred2[1] + wred2[2] + wred2[3];
    int excl = v + wpre - d;

    float dv = rsqrtf((float)d);
    if (valid) {
        csrOff[n] = bb + excl;
        dis[n] = dv;
    }
    if (b == 0 && t == 0) csrOff[N_NODES] = CSR_LEN;
    cur[t] = excl;
    __syncthreads();
    if (valid) {
        int pos = atomicAdd(&cur[t], 1);
        slice[pos] = n;
    }
    for (int i = t; i < cnt; i += 256) {
        int rec = regions[b * REGION + i];
        int pos = atomicAdd(&cur[rec >> 17], 1);
        slice[pos] = rec & 0x1FFFF;
    }
    __syncthreads();
    for (int i = t; i < tot; i += 256) csrSrc[bb + i] = slice[i];

    // ---- premsg tail: m[n] = BN(x[n]) * dis[n] (f16); zero dummy row N_NODES ----
    if (valid) {
        const float4* xr = (const float4*)x + (size_t)n * 4;
        half4* mr = m4 + (size_t)n * 4;
#pragma unroll
        for (int c = 0; c < 4; c++) {
            float4 h = xr[c];
            half4 o;
            o.x = (_Float16)((h.x * sc16[c * 4 + 0] + sh16[c * 4 + 0]) * dv);
            o.y = (_Float16)((h.y * sc16[c * 4 + 1] + sh16[c * 4 + 1]) * dv);
            o.z = (_Float16)((h.z * sc16[c * 4 + 2] + sh16[c * 4 + 2]) * dv);
            o.w = (_Float16)((h.w * sc16[c * 4 + 3] + sh16[c * 4 + 3]) * dv);
            mr[c] = o;
        }
    } else if (n == N_NODES) {
        half4 z;
        z.x = (_Float16)0.f; z.y = (_Float16)0.f; z.z = (_Float16)0.f; z.w = (_Float16)0.f;
        half4* mr = m4 + (size_t)n * 4;
#pragma unroll
        for (int c = 0; c < 4; c++) mr[c] = z;
    }
}

// ---------------- BN coefficient helpers ----------------

__device__ __forceinline__ void bn_coef_rep(const float* rep, const float* gamma,
                                            const float* beta, int k, float& sc, float& sh) {
    float S = 0.f, Q = 0.f;
    for (int r = 0; r < NREP; r++) { S += rep[r * 128 + k]; Q += rep[r * 128 + 64 + k]; }
    const float invn = 1.0f / (float)N_NODES;
    float m = S * invn;
    float var = Q * invn - m * m;
    float rs = rsqrtf(var + EPS);
    sc = gamma[k] * rs;
    sh = beta[k] - m * sc;
}

// ---------------- device-scope grid barrier (RELAXED spin — no per-iter buffer_inv) ------
// gbar layout per id: [id*64] counter, [id*64+32] flag; zeroed by memset.

__device__ __forceinline__ void gridbar(int* gbar, int id) {
    __syncthreads();
    if (threadIdx.x == 0) {
        __threadfence();  // release: L2 writeback (once)
        int* cnt = &gbar[id * 64];
        int* flg = &gbar[id * 64 + 32];
        int v = __hip_atomic_fetch_add(cnt, 1, __ATOMIC_RELAXED, __HIP_MEMORY_SCOPE_AGENT);
        if (v == MEGA_BLOCKS - 1) {
            __hip_atomic_store(flg, 1, __ATOMIC_RELAXED, __HIP_MEMORY_SCOPE_AGENT);
        } else {
            // RELAXED agent-scope load: coherent (bypasses L1), emits NO buffer_inv
            while (!__hip_atomic_load(flg, __ATOMIC_RELAXED, __HIP_MEMORY_SCOPE_AGENT))
                __builtin_amdgcn_s_sleep(8);
        }
        __threadfence();  // acquire: invalidate stale lines (once)
    }
    __syncthreads();
}

// ---------------- mega kernel phase helpers (SM = 4352-float shared scratch) ----------------

__device__ void gemm_phase(const _Float16* __restrict__ hin, const float* __restrict__ W,
                           const float* __restrict__ rep, const float* __restrict__ gamma,
                           const float* __restrict__ beta, const float* __restrict__ dis,
                           _Float16* __restrict__ hout, float* SM) {
    const int t = threadIdx.x;
    float* hs = SM;               // [64][66]
    float* scb = SM + 4224;
    float* shb = SM + 4288;
    if (t < 64) bn_coef_rep(rep, gamma, beta, t, scb[t], shb[t]);
    __syncthreads();
    const int fg = t & 15;
    const int rg = t >> 4;
    const float4* W4 = (const float4*)W;
    const half4* hin4 = (const half4*)hin;
    half4* hout4 = (half4*)hout;
    const int nvb = (N_NODES + 63) / 64;  // 1563
    for (int vb = blockIdx.x; vb < nvb; vb += MEGA_BLOCKS) {
        int base = vb * 64;
        for (int i = t; i < 64 * 16; i += 256) {
            int r = i >> 4, c = i & 15;
            int n = base + r;
            float4 v = make_float4(0.f, 0.f, 0.f, 0.f);
            if (n < N_NODES) {
                half4 h = hin4[n * 16 + c];
                v.x = fmaxf((float)h.x * scb[c * 4 + 0] + shb[c * 4 + 0], 0.f);
                v.y = fmaxf((float)h.y * scb[c * 4 + 1] + shb[c * 4 + 1], 0.f);
                v.z = fmaxf((float)h.z * scb[c * 4 + 2] + shb[c * 4 + 2], 0.f);
                v.w = fmaxf((float)h.w * scb[c * 4 + 3] + shb[c * 4 + 3], 0.f);
            }
            hs[r * 66 + c * 4 + 0] = v.x;
            hs[r * 66 + c * 4 + 1] = v.y;
            hs[r * 66 + c * 4 + 2] = v.z;
            hs[r * 66 + c * 4 + 3] = v.w;
        }
        __syncthreads();
        float4 acc[4];
#pragma unroll
        for (int r = 0; r < 4; r++) acc[r] = make_float4(0.f, 0.f, 0.f, 0.f);
        for (int k = 0; k < HID; k += 2) {
            float4 wk0 = W4[k * 16 + fg];
            float4 wk1 = W4[(k + 1) * 16 + fg];
#pragma unroll
            for (int r = 0; r < 4; r++) {
                float2 h2 = *(const float2*)&hs[(rg * 4 + r) * 66 + k];
                acc[r].x += h2.x * wk0.x + h2.y * wk1.x;
                acc[r].y += h2.x * wk0.y + h2.y * wk1.y;
                acc[r].z += h2.x * wk0.z + h2.y * wk1.z;
                acc[r].w += h2.x * wk0.w + h2.y * wk1.w;
            }
        }
#pragma unroll
        for (int r = 0; r < 4; r++) {
            int n = base + rg * 4 + r;
            if (n < N_NODES) {
                float dsc = dis[n];
                half4 o;
                o.x = (_Float16)(acc[r].x * dsc);
                o.y = (_Float16)(acc[r].y * dsc);
                o.z = (_Float16)(acc[r].z * dsc);
                o.w = (_Float16)(acc[r].w * dsc);
                hout4[n * 16 + fg] = o;
            }
        }
        __syncthreads();  // protect hs before next tile
    }
}

__device__ void agg64_phase(const half8* __restrict__ hwh, const int* __restrict__ csrOff,
                            const int* __restrict__ csrSrc, const float* __restrict__ dis,
                            const float* __restrict__ bias, half8* __restrict__ y8,
                            float* __restrict__ statsRep, float* SM) {
    const int lane = threadIdx.x & 63;
    const int wid = threadIdx.x >> 6;
    const int g = lane >> 5;
    const int s = lane & 31;
    const int c = s & 7;
    const int o = s >> 3;
    const int wave = blockIdx.x * 4 + wid;

    const float4 bv0 = ((const float4*)bias)[c * 2];
    const float4 bv1 = ((const float4*)bias)[c * 2 + 1];
    float sa[8], qa[8];
#pragma unroll
    for (int j = 0; j < 8; j++) { sa[j] = 0.f; qa[j] = 0.f; }

    for (int n0 = wave * 2; n0 < N_NODES; n0 += MEGA_WAVES * 2) {
        int n = n0 + g;
        bool vn = (n < N_NODES);
        int beg = 0, end = 0;
        if (vn) { beg = csrOff[n]; end = csrOff[n + 1]; }
        float acc[8];
#pragma unroll
        for (int j = 0; j < 8; j++) acc[j] = 0.f;
        int e = beg + o;
        int i0 = (e < end) ? csrSrc[e] : N_NODES;
        int i1 = (e + 4 < end) ? csrSrc[e + 4] : N_NODES;
        while (e < end) {
            int j0 = i0, j1 = i1;
            e += 8;
            i0 = (e < end) ? csrSrc[e] : N_NODES;
            i1 = (e + 4 < end) ? csrSrc[e + 4] : N_NODES;
            half8 h0 = hwh[(size_t)j0 * 8 + c];
            half8 h1 = hwh[(size_t)j1 * 8 + c];
#pragma unroll
            for (int j = 0; j < 8; j++) acc[j] += (float)h0[j] + (float)h1[j];
        }
#pragma unroll
        for (int j = 0; j < 8; j++) {
            acc[j] += __shfl_xor(acc[j], 8, 64);
            acc[j] += __shfl_xor(acc[j], 16, 64);
        }
        if (o == 0 && vn) {
            float d = dis[n];
            float val[8];
            val[0] = acc[0] * d + bv0.x; val[1] = acc[1] * d + bv0.y;
            val[2] = acc[2] * d + bv0.z; val[3] = acc[3] * d + bv0.w;
            val[4] = acc[4] * d + bv1.x; val[5] = acc[5] * d + bv1.y;
            val[6] = acc[6] * d + bv1.z; val[7] = acc[7] * d + bv1.w;
            half8 ov;
#pragma unroll
            for (int j = 0; j < 8; j++) ov[j] = (_Float16)val[j];
            y8[(size_t)n * 8 + c] = ov;
#pragma unroll
            for (int j = 0; j < 8; j++) { sa[j] += val[j]; qa[j] += val[j] * val[j]; }
        }
    }
#pragma unroll
    for (int j = 0; j < 8; j++) {
        sa[j] += __shfl_xor(sa[j], 32, 64);
        qa[j] += __shfl_xor(qa[j], 32, 64);
    }
    float* ls = SM;          // [4][64]
    float* lq = SM + 256;    // [4][64]
    ls[wid * 64 + lane] = 0.f;
    lq[wid * 64 + lane] = 0.f;
    if (lane < 8) {
#pragma unroll
        for (int j = 0; j < 8; j++) {
            ls[wid * 64 + lane * 8 + j] = sa[j];
            lq[wid * 64 + lane * 8 + j] = qa[j];
        }
    }
    __syncthreads();
    if (wid == 0) {
        float S = ls[lane] + ls[64 + lane] + ls[128 + lane] + ls[192 + lane];
        float Q = lq[lane] + lq[64 + lane] + lq[128 + lane] + lq[192 + lane];
        float* rep = statsRep + (blockIdx.x & (NREP - 1)) * 128;
        atomicAdd(&rep[lane], S);
        atomicAdd(&rep[64 + lane], Q);
    }
    __syncthreads();  // release SM
}

// ---------------- the mega kernel: agg16·W0 .. head, 6 grid barriers ----------------

__global__ __launch_bounds__(256, 4) void mega_kernel(
    const float* __restrict__ dis, const int* __restrict__ csrOff,
    const int* __restrict__ csrSrc, const _Float16* __restrict__ msgBuf,
    const float* __restrict__ W0, const float* __restrict__ b0,
    _Float16* __restrict__ yBuf, _Float16* __restrict__ hwBuf,
    float* __restrict__ statsRep,
    const float* __restrict__ W1, const float* __restrict__ b1,
    const float* __restrict__ g0, const float* __restrict__ be0,
    const float* __restrict__ W2, const float* __restrict__ b2,
    const float* __restrict__ g1, const float* __restrict__ be1,
    const float* __restrict__ g2, const float* __restrict__ be2,
    const int* __restrict__ batch, float* __restrict__ pool, float* __restrict__ cnt,
    const float* __restrict__ Wc1, const float* __restrict__ bc1,
    const float* __restrict__ Wc2, const float* __restrict__ bc2,
    float* __restrict__ out, int* __restrict__ gbar) {
    __shared__ float SM[4352];
    const int t = threadIdx.x;
    float* rep1 = statsRep;
    float* rep2 = statsRep + NREP * 128;
    float* rep3 = statsRep + 2 * NREP * 128;

    // ---- P1: fused 16-dim aggregate + W0 GEMM -> yBuf, rep1 ----
    {
        const int lane = t & 63;
        const int wid = t >> 6;
        const int g = lane >> 4;
        const int s = lane & 15;
        const int fl = s & 3;
        const int q = s >> 2;
        const int wave = blockIdx.x * 4 + wid;
        const half4* m4 = (const half4*)msgBuf;

        float wreg[16][4];
#pragma unroll
        for (int k = 0; k < 16; k++) {
#pragma unroll
            for (int j = 0; j < 4; j++) wreg[k][j] = W0[k * HID + s + 16 * j];
        }
        float bj[4];
#pragma unroll
        for (int j = 0; j < 4; j++) bj[j] = b0[s + 16 * j];
        float sv[4] = {0.f, 0.f, 0.f, 0.f}, qv[4] = {0.f, 0.f, 0.f, 0.f};

        for (int n0 = wave * 4; n0 < N_NODES; n0 += MEGA_WAVES * 4) {
            int n = n0 + g;
            bool vn = (n < N_NODES);
            int beg = 0, end = 0;
            if (vn) { beg = csrOff[n]; end = csrOff[n + 1]; }
            float4 acc = make_float4(0.f, 0.f, 0.f, 0.f);
            int e = beg + q;
            int i0 = (e < end) ? csrSrc[e] : N_NODES;
            int i1 = (e + 4 < end) ? csrSrc[e + 4] : N_NODES;
            while (e < end) {
                int j0 = i0, j1 = i1;
                e += 8;
                i0 = (e < end) ? csrSrc[e] : N_NODES;
                i1 = (e + 4 < end) ? csrSrc[e + 4] : N_NODES;
                half4 v0 = m4[(size_t)j0 * 4 + fl];
                half4 v1 = m4[(size_t)j1 * 4 + fl];
                acc.x += (float)v0.x + (float)v1.x;
                acc.y += (float)v0.y + (float)v1.y;
                acc.z += (float)v0.z + (float)v1.z;
                acc.w += (float)v0.w + (float)v1.w;
            }
            acc.x += __shfl_xor(acc.x, 4, 64);  acc.y += __shfl_xor(acc.y, 4, 64);
            acc.z += __shfl_xor(acc.z, 4, 64);  acc.w += __shfl_xor(acc.w, 4, 64);
            acc.x += __shfl_xor(acc.x, 8, 64);  acc.y += __shfl_xor(acc.y, 8, 64);
            acc.z += __shfl_xor(acc.z, 8, 64);  acc.w += __shfl_xor(acc.w, 8, 64);
            float d = vn ? dis[n] : 0.f;
            acc.x *= d; acc.y *= d; acc.z *= d; acc.w *= d;
            float yv0 = bj[0], yv1 = bj[1], yv2 = bj[2], yv3 = bj[3];
            const int gbase = lane & 48;
#pragma unroll
            for (int k = 0; k < 16; k++) {
                float comp = ((k & 3) == 0) ? acc.x : ((k & 3) == 1) ? acc.y
                            : ((k & 3) == 2) ? acc.z : acc.w;
                float a = __shfl(comp, gbase + (k >> 2), 64);
                yv0 += a * wreg[k][0];
                yv1 += a * wreg[k][1];
                yv2 += a * wreg[k][2];
                yv3 += a * wreg[k][3];
            }
            if (vn) {
                _Float16* yr = yBuf + (size_t)n * HID;
                yr[s] = (_Float16)yv0; yr[s + 16] = (_Float16)yv1;
                yr[s + 32] = (_Float16)yv2; yr[s + 48] = (_Float16)yv3;
                sv[0] += yv0; qv[0] += yv0 * yv0;
                sv[1] += yv1; qv[1] += yv1 * yv1;
                sv[2] += yv2; qv[2] += yv2 * yv2;
                sv[3] += yv3; qv[3] += yv3 * yv3;
            }
        }
#pragma unroll
        for (int j = 0; j < 4; j++) {
            sv[j] += __shfl_xor(sv[j], 16, 64); sv[j] += __shfl_xor(sv[j], 32, 64);
            qv[j] += __shfl_xor(qv[j], 16, 64); qv[j] += __shfl_xor(qv[j], 32, 64);
        }
        float* ls = SM;        // [4][64]
        float* lq = SM + 256;  // [4][64]
        if (g == 0) {
#pragma unroll
            for (int j = 0; j < 4; j++) {
                ls[wid * 64 + s + 16 * j] = sv[j];
                lq[wid * 64 + s + 16 * j] = qv[j];
            }
        }
        __syncthreads();
        if (wid == 0) {
            float S = ls[lane] + ls[64 + lane] + ls[128 + lane] + ls[192 + lane];
            float Q = lq[lane] + lq[64 + lane] + lq[128 + lane] + lq[192 + lane];
            float* rep = rep1 + (blockIdx.x & (NREP - 1)) * 128;
            atomicAdd(&rep[lane], S);
            atomicAdd(&rep[64 + lane], Q);
        }
    }
    gridbar(gbar, 0);

    // ---- P2: gemm layer1 (yBuf -> hwBuf) ----
    gemm_phase(yBuf, W1, rep1, g0, be0, dis, hwBuf, SM);
    gridbar(gbar, 1);

    // ---- P3: aggregate layer1 (hwBuf -> yBuf, rep2) ----
    agg64_phase((const half8*)hwBuf, csrOff, csrSrc, dis, b1, (half8*)yBuf, rep2, SM);
    gridbar(gbar, 2);

    // ---- P4: gemm layer2 (yBuf -> hwBuf) ----
    gemm_phase(yBuf, W2, rep2, g1, be1, dis, hwBuf, SM);
    gridbar(gbar, 3);

    // ---- P5: aggregate layer2 (hwBuf -> yBuf, rep3) ----
    agg64_phase((const half8*)hwBuf, csrOff, csrSrc, dis, b2, (half8*)yBuf, rep3, SM);
    gridbar(gbar, 4);

    // ---- P6: pool (BN(rep3)+relu fused) ----
    {
        float* scs = SM;
        float* shs = SM + 64;
        if (t < 64) bn_coef_rep(rep3, g2, be2, t, scs[t], shs[t]);
        __syncthreads();
        const int f = t & 63;
        const int nl = t >> 6;
        float sc = scs[f], sh = shs[f];
        const int nbPool = (N_NODES + 255) / 256;
        for (int vb = blockIdx.x; vb < nbPool; vb += MEGA_BLOCKS) {
            int base = vb * 256;
            int endn = min(base + 256, N_NODES);
            int g_cur = -1;
            float acc = 0.f, c_acc = 0.f;
            for (int n = base + nl; n < endn; n += 4) {
                int gg = batch[n];
                float v = fmaxf((float)yBuf[(size_t)n * HID + f] * sc + sh, 0.f);
                if (gg != g_cur) {
                    if (g_cur >= 0) {
                        atomicAdd(&pool[g_cur * HID + f], acc);
                        if (f == 0) atomicAdd(&cnt[g_cur], c_acc);
                    }
                    g_cur = gg;
                    acc = 0.f;
                    c_acc = 0.f;
                }
                acc += v;
                c_acc += 1.f;
            }
            if (g_cur >= 0) {
                atomicAdd(&pool[g_cur * HID + f], acc);
                if (f == 0) atomicAdd(&cnt[g_cur], c_acc);
            }
        }
        __syncthreads();
    }
    gridbar(gbar, 5);

    // ---- P7: head ----
    if (blockIdx.x < N_GRAPHS) {
        int g = blockIdx.x;
        float* p = SM;
        float* z = SM + 64;
        if (t < 64) {
            float c = fmaxf(cnt[g], 1.0f);
            p[t] = pool[g * HID + t] / c;
        }
        __syncthreads();
        if (t < 64) {
            float acc = bc1[t];
            for (int k = 0; k < 64; k++) acc += p[k] * Wc1[k * 64 + t];
            z[t] = fmaxf(acc, 0.f);
        }
        __syncthreads();
        if (t < 2) {
            float o = bc2[t];
            for (int k = 0; k < 64; k++) o += z[k] * Wc2[k * 2 + t];
            out[g * 2 + t] = o;
        }
    }
}

// ---------------- launch ----------------

extern "C" void kernel_launch(void* const* d_in, const int* in_sizes, int n_in,
                              void* d_out, int out_size, void* d_ws, size_t ws_size,
                              hipStream_t stream) {
    const float* x      = (const float*)d_in[0];
    const int*   ei     = (const int*)d_in[1];
    const int*   batch  = (const int*)d_in[2];
    const float* bn_in_g = (const float*)d_in[3];
    const float* bn_in_b = (const float*)d_in[4];
    const float* W0 = (const float*)d_in[5];
    const float* b0 = (const float*)d_in[6];
    const float* g0 = (const float*)d_in[7];
    const float* be0 = (const float*)d_in[8];
    const float* W1 = (const float*)d_in[9];
    const float* b1 = (const float*)d_in[10];
    const float* g1 = (const float*)d_in[11];
    const float* be1 = (const float*)d_in[12];
    const float* W2 = (const float*)d_in[13];
    const float* b2 = (const float*)d_in[14];
    const float* g2 = (const float*)d_in[15];
    const float* be2 = (const float*)d_in[16];
    const float* Wc1 = (const float*)d_in[17];
    const float* bc1 = (const float*)d_in[18];
    const float* Wc2 = (const float*)d_in[19];
    const float* bc2 = (const float*)d_in[20];
    float* out = (float*)d_out;

    char* w = (char*)d_ws;
    size_t off = 0;
    auto take = [&](size_t bytes) {
        size_t r = off;
        off += (bytes + 255) & ~(size_t)255;
        return r;
    };
    // ---- zero region (one memset) ----
    float* stats    = (float*)(w + take(256 * 4));             // s0: [sums 64][sumsq 64]
    float* statsRep = (float*)(w + take(3 * NREP * 128 * 4));  // replicated accumulators
    float* pool     = (float*)(w + take((size_t)N_GRAPHS * HID * 4));
    float* cnt      = (float*)(w + take((size_t)N_GRAPHS * 4));
    int* bucketCnt  = (int*)(w + take((size_t)NB_BUCKETS * 4));
    int* gbar       = (int*)(w + take(8 * 64 * 4));            // grid barriers
    size_t zero_end = off;
    // ---- rest ----
    float* dis    = (float*)(w + take((size_t)N_NODES * 4));
    int* csrOff   = (int*)(w + take((size_t)(N_NODES + 1) * 4));
    int* csrSrc   = (int*)(w + take((size_t)(CSR_LEN + 64) * 4));
    _Float16* hwBuf = (_Float16*)(w + take((size_t)(N_NODES + 1) * HID * 2));  // f16 msgs +dummy
    _Float16* yBuf  = (_Float16*)(w + take((size_t)N_NODES * HID * 2));        // f16 activations
    _Float16* msgBuf = (_Float16*)(w + take((size_t)(N_NODES + 1) * IN_DIM * 2));  // f16 16-dim
    int* regions  = (int*)hwBuf;   // alias: consumed by build_kernel before gemm writes
    (void)ws_size; (void)n_in; (void)in_sizes; (void)out_size;

    hipMemsetAsync(w, 0, zero_end, stream);

    const int nbBin = (N_EDGES + BIN_TILE - 1) / BIN_TILE;  // 293
    float* s0 = stats;

    // CSR build (bucketed; self-loops folded in) + input BN stats
    bin_stats_kernel<<<nbBin + STATS_BLKS, 256, 0, stream>>>(ei, bucketCnt, regions, x, s0,
                                                             s0 + 64, hwBuf, nbBin);
    // build CSR + fused premsg tail (dis in-register)
    build_kernel<<<NB_BUCKETS, 256, 0, stream>>>(regions, bucketCnt, csrOff, csrSrc, dis, x,
                                                 s0, s0 + 64, bn_in_g, bn_in_b,
                                                 (half4*)msgBuf);

    // everything else: one persistent kernel, 6 device-scope grid barriers
    mega_kernel<<<MEGA_BLOCKS, 256, 0, stream>>>(
        dis, csrOff, csrSrc, msgBuf, W0, b0, yBuf, hwBuf, statsRep,
        W1, b1, g0, be0, W2, b2, g1, be1, g2, be2, batch, pool, cnt, Wc1, bc1, Wc2, bc2,
        out, gbar);
}

// Round 7
// 304.159 us; speedup vs baseline: 7.0987x; 1.7952x over previous
//
#include <hip/hip_runtime.h>
#include <hip/hip_bf16.h>

#define N_NODES 100000
#define N_EDGES 1200000
#define N_GRAPHS 512
#define HID 64
#define IN_DIM 16
#define EPS 1e-5f

#define NB_BUCKETS 391   // ceil(N_NODES / BUCKET_SPAN)
#define BUCKET_SPAN 256  // dst >> 8
#define REGION 4096      // per-bucket region capacity (avg real fill ~3069)
#define BIN_TILE 4096    // edges per bin block
#define CSR_LEN (N_EDGES + N_NODES)  // self-loops folded in
#define NREP 64          // stats replicas (atomic de-contention)
#define STATS_BLKS 64    // extra blocks appended to bin grid for input-BN stats

typedef _Float16 half4 __attribute__((ext_vector_type(4)));
typedef _Float16 half8 __attribute__((ext_vector_type(8)));

// ------------- bin (edge bucketing) + input-BN stats (merged independent work) -------------

__global__ void bin_stats_kernel(const int* __restrict__ ei, int* __restrict__ bucketCnt,
                                 int* __restrict__ regions, const float* __restrict__ x,
                                 float* __restrict__ sums, float* __restrict__ sumsq,
                                 _Float16* __restrict__ hwBuf, int nbBin) {
    __shared__ int hist[NB_BUCKETS], basem[NB_BUCKETS], cur[NB_BUCKETS];
    __shared__ float ls[16], lq[16];
    int t = threadIdx.x;

    if (blockIdx.x >= nbBin) {
        // ---- stats path: float4 loads; residue class (i&3) fixed per thread ----
        const int sblk = blockIdx.x - nbBin;
        if (sblk == 0 && t < 8)  // zero f16 dummy gather row of hwBuf (beyond regions alias)
            ((float4*)(hwBuf + (size_t)N_NODES * HID))[t] = make_float4(0.f, 0.f, 0.f, 0.f);
        if (t < 16) { ls[t] = 0.f; lq[t] = 0.f; }
        __syncthreads();
        const float4* x4 = (const float4*)x;
        const int total4 = N_NODES * IN_DIM / 4;  // 400000
        float s0 = 0.f, s1 = 0.f, s2 = 0.f, s3 = 0.f;
        float q0 = 0.f, q1 = 0.f, q2 = 0.f, q3 = 0.f;
        int i = sblk * 256 + t;
        const int fb = (i & 3) * 4;  // stride 16384 ≡ 0 mod 4 → invariant
        for (; i < total4; i += STATS_BLKS * 256) {
            float4 v = x4[i];
            s0 += v.x; q0 += v.x * v.x;
            s1 += v.y; q1 += v.y * v.y;
            s2 += v.z; q2 += v.z * v.z;
            s3 += v.w; q3 += v.w * v.w;
        }
        atomicAdd(&ls[fb + 0], s0); atomicAdd(&lq[fb + 0], q0);
        atomicAdd(&ls[fb + 1], s1); atomicAdd(&lq[fb + 1], q1);
        atomicAdd(&ls[fb + 2], s2); atomicAdd(&lq[fb + 2], q2);
        atomicAdd(&ls[fb + 3], s3); atomicAdd(&lq[fb + 3], q3);
        __syncthreads();
        if (t < 16) { atomicAdd(&sums[t], ls[t]); atomicAdd(&sumsq[t], lq[t]); }
        return;
    }

    // ---- bin path ----
    for (int i = t; i < NB_BUCKETS; i += 256) { hist[i] = 0; cur[i] = 0; }
    __syncthreads();
    const int4* ei4s = (const int4*)ei;
    const int4* ei4d = (const int4*)(ei + N_EDGES);
    int srcs[16], dsts[16];
#pragma unroll
    for (int i = 0; i < 4; i++) {
        int idx4 = blockIdx.x * (BIN_TILE / 4) + t + i * 256;
        if (idx4 * 4 < N_EDGES) {
            int4 s4 = ei4s[idx4];
            int4 d4 = ei4d[idx4];
            srcs[i * 4 + 0] = s4.x; dsts[i * 4 + 0] = d4.x;
            srcs[i * 4 + 1] = s4.y; dsts[i * 4 + 1] = d4.y;
            srcs[i * 4 + 2] = s4.z; dsts[i * 4 + 2] = d4.z;
            srcs[i * 4 + 3] = s4.w; dsts[i * 4 + 3] = d4.w;
            atomicAdd(&hist[d4.x >> 8], 1);
            atomicAdd(&hist[d4.y >> 8], 1);
            atomicAdd(&hist[d4.z >> 8], 1);
            atomicAdd(&hist[d4.w >> 8], 1);
        } else {
            dsts[i * 4 + 0] = -1; dsts[i * 4 + 1] = -1;
            dsts[i * 4 + 2] = -1; dsts[i * 4 + 3] = -1;
        }
    }
    __syncthreads();
    for (int i = t; i < NB_BUCKETS; i += 256) {
        int h = hist[i];
        basem[i] = h ? atomicAdd(&bucketCnt[i], h) : 0;
    }
    __syncthreads();
#pragma unroll
    for (int i = 0; i < 16; i++) {
        if (dsts[i] >= 0) {
            int b = dsts[i] >> 8;
            int pos = basem[b] + atomicAdd(&cur[b], 1);
            if (pos < REGION)
                regions[b * REGION + pos] = srcs[i] | ((dsts[i] & 255) << 17);
        }
    }
}

// ------------- CSR build (wave-shfl scans) + fused premsg tail -------------

__global__ void build_kernel(const int* __restrict__ regions, const int* __restrict__ bucketCnt,
                             int* __restrict__ csrOff, int* __restrict__ csrSrc,
                             float* __restrict__ dis, const float* __restrict__ x,
                             const float* __restrict__ sums, const float* __restrict__ sumsq,
                             const float* __restrict__ gamma, const float* __restrict__ beta,
                             half4* __restrict__ m4) {
    __shared__ int deg[256], cur[256];
    __shared__ int slice[REGION + 256];
    __shared__ int wred1[4], wred2[4];
    __shared__ float sc16[16], sh16[16];
    int b = blockIdx.x, t = threadIdx.x;
    const int laneid = t & 63;
    const int w = t >> 6;

    if (t < 16) {  // BN coefs for premsg tail (stats final: prior dispatch)
        const float invn = 1.0f / (float)N_NODES;
        float m = sums[t] * invn;
        float var = sumsq[t] * invn - m * m;
        float rs = rsqrtf(var + EPS);
        sc16[t] = gamma[t] * rs;
        sh16[t] = beta[t] - m * sc16[t];
    }
    {
        int s = 0;
        for (int i = t; i < NB_BUCKETS; i += 256)
            if (i < b) s += min(bucketCnt[i], REGION);
#pragma unroll
        for (int d = 1; d < 64; d <<= 1) s += __shfl_xor(s, d, 64);
        if (laneid == 0) wred1[w] = s;
    }
    int cnt = min(bucketCnt[b], REGION);
    int nbase = b * BUCKET_SPAN;
    int n = nbase + t;
    bool valid = (n < N_NODES);
    deg[t] = valid ? 1 : 0;  // self loop
    __syncthreads();
    const int bb = wred1[0] + wred1[1] + wred1[2] + wred1[3] + b * BUCKET_SPAN;

    for (int i = t; i < cnt; i += 256) {
        int rec = regions[b * REGION + i];
        atomicAdd(&deg[rec >> 17], 1);
    }
    __syncthreads();
    int d = deg[t];

    // 256-wide exclusive scan via wave inclusive scans (2 barriers)
    int v = d;
#pragma unroll
    for (int sh = 1; sh < 64; sh <<= 1) {
        int u = __shfl_up(v, sh, 64);
        if (laneid >= sh) v += u;
    }
    if (laneid == 63) wred2[w] = v;
    __syncthreads();
    int wpre = 0;
#pragma unroll
    for (int ww = 0; ww < 4; ww++)
        if (ww < w) wpre += wred2[ww];
    const int tot = wred2[0] + wred2[1] + wred2[2] + wred2[3];
    int excl = v + wpre - d;

    float dv = rsqrtf((float)d);
    if (valid) {
        csrOff[n] = bb + excl;
        dis[n] = dv;
    }
    if (b == 0 && t == 0) csrOff[N_NODES] = CSR_LEN;
    cur[t] = excl;
    __syncthreads();
    if (valid) {
        int pos = atomicAdd(&cur[t], 1);
        slice[pos] = n;
    }
    for (int i = t; i < cnt; i += 256) {
        int rec = regions[b * REGION + i];
        int pos = atomicAdd(&cur[rec >> 17], 1);
        slice[pos] = rec & 0x1FFFF;
    }
    __syncthreads();
    for (int i = t; i < tot; i += 256) csrSrc[bb + i] = slice[i];

    // ---- premsg tail: m[n] = BN(x[n]) * dis[n] (f16); zero dummy row N_NODES ----
    if (valid) {
        const float4* xr = (const float4*)x + (size_t)n * 4;
        half4* mr = m4 + (size_t)n * 4;
#pragma unroll
        for (int c = 0; c < 4; c++) {
            float4 h = xr[c];
            half4 o;
            o.x = (_Float16)((h.x * sc16[c * 4 + 0] + sh16[c * 4 + 0]) * dv);
            o.y = (_Float16)((h.y * sc16[c * 4 + 1] + sh16[c * 4 + 1]) * dv);
            o.z = (_Float16)((h.z * sc16[c * 4 + 2] + sh16[c * 4 + 2]) * dv);
            o.w = (_Float16)((h.w * sc16[c * 4 + 3] + sh16[c * 4 + 3]) * dv);
            mr[c] = o;
        }
    } else if (n == N_NODES) {
        half4 z;
        z.x = (_Float16)0.f; z.y = (_Float16)0.f; z.z = (_Float16)0.f; z.w = (_Float16)0.f;
        half4* mr = m4 + (size_t)n * 4;
#pragma unroll
        for (int c = 0; c < 4; c++) mr[c] = z;
    }
}

// ---------------- BN coefficient helpers ----------------

// reduce replicas + bn finalize for feature k (k < 64)
__device__ __forceinline__ void bn_coef_rep(const float* rep, const float* gamma,
                                            const float* beta, int k, float& sc, float& sh) {
    float S = 0.f, Q = 0.f;
    for (int r = 0; r < NREP; r++) { S += rep[r * 128 + k]; Q += rep[r * 128 + 64 + k]; }
    const float invn = 1.0f / (float)N_NODES;
    float m = S * invn;
    float var = Q * invn - m * m;
    float rs = rsqrtf(var + EPS);
    sc = gamma[k] * rs;
    sh = beta[k] - m * sc;
}

// ---------------- Layer 0: fused aggregate16·W0 (4 nodes/wave, W0 in registers) --------

__global__ void agg16_gemm0_kernel(const half4* __restrict__ m4, const int* __restrict__ csrOff,
                                   const int* __restrict__ csrSrc, const float* __restrict__ dis,
                                   const float* __restrict__ W, const float* __restrict__ bias,
                                   _Float16* __restrict__ y, float* __restrict__ statsRep) {
    const int t = threadIdx.x;
    const int lane = t & 63;
    const int wid = t >> 6;
    const int g = lane >> 4;     // node subgroup 0..3
    const int s = lane & 15;     // lane within group
    const int fl = s & 3;        // half4 column (dims 4fl..4fl+3)
    const int q = s >> 2;        // edge slot 0..3
    const int wave = blockIdx.x * 4 + wid;
    const int nwaves = gridDim.x * 4;

    float wreg[16][4];
#pragma unroll
    for (int k = 0; k < 16; k++) {
#pragma unroll
        for (int j = 0; j < 4; j++) wreg[k][j] = W[k * HID + s + 16 * j];
    }
    float bj[4];
#pragma unroll
    for (int j = 0; j < 4; j++) bj[j] = bias[s + 16 * j];
    float sv[4] = {0.f, 0.f, 0.f, 0.f}, qv[4] = {0.f, 0.f, 0.f, 0.f};

    for (int n0 = wave * 4; n0 < N_NODES; n0 += nwaves * 4) {
        int n = n0 + g;
        bool vn = (n < N_NODES);
        int beg = 0, end = 0;
        if (vn) { beg = csrOff[n]; end = csrOff[n + 1]; }
        float4 acc = make_float4(0.f, 0.f, 0.f, 0.f);
        int e = beg + q;
        int i0 = (e < end) ? csrSrc[e] : N_NODES;
        int i1 = (e + 4 < end) ? csrSrc[e + 4] : N_NODES;
        while (e < end) {
            int j0 = i0, j1 = i1;
            e += 8;
            i0 = (e < end) ? csrSrc[e] : N_NODES;
            i1 = (e + 4 < end) ? csrSrc[e + 4] : N_NODES;
            half4 v0 = m4[(size_t)j0 * 4 + fl];
            half4 v1 = m4[(size_t)j1 * 4 + fl];
            acc.x += (float)v0.x + (float)v1.x;
            acc.y += (float)v0.y + (float)v1.y;
            acc.z += (float)v0.z + (float)v1.z;
            acc.w += (float)v0.w + (float)v1.w;
        }
        acc.x += __shfl_xor(acc.x, 4, 64);  acc.y += __shfl_xor(acc.y, 4, 64);
        acc.z += __shfl_xor(acc.z, 4, 64);  acc.w += __shfl_xor(acc.w, 4, 64);
        acc.x += __shfl_xor(acc.x, 8, 64);  acc.y += __shfl_xor(acc.y, 8, 64);
        acc.z += __shfl_xor(acc.z, 8, 64);  acc.w += __shfl_xor(acc.w, 8, 64);
        float d = vn ? dis[n] : 0.f;
        acc.x *= d; acc.y *= d; acc.z *= d; acc.w *= d;
        float yv0 = bj[0], yv1 = bj[1], yv2 = bj[2], yv3 = bj[3];
        const int gbase = lane & 48;  // 16*g
#pragma unroll
        for (int k = 0; k < 16; k++) {
            float comp = ((k & 3) == 0) ? acc.x : ((k & 3) == 1) ? acc.y
                        : ((k & 3) == 2) ? acc.z : acc.w;
            float a = __shfl(comp, gbase + (k >> 2), 64);
            yv0 += a * wreg[k][0];
            yv1 += a * wreg[k][1];
            yv2 += a * wreg[k][2];
            yv3 += a * wreg[k][3];
        }
        if (vn) {
            _Float16* yr = y + (size_t)n * HID;
            yr[s] = (_Float16)yv0; yr[s + 16] = (_Float16)yv1;
            yr[s + 32] = (_Float16)yv2; yr[s + 48] = (_Float16)yv3;
            sv[0] += yv0; qv[0] += yv0 * yv0;
            sv[1] += yv1; qv[1] += yv1 * yv1;
            sv[2] += yv2; qv[2] += yv2 * yv2;
            sv[3] += yv3; qv[3] += yv3 * yv3;
        }
    }
#pragma unroll
    for (int j = 0; j < 4; j++) {
        sv[j] += __shfl_xor(sv[j], 16, 64); sv[j] += __shfl_xor(sv[j], 32, 64);
        qv[j] += __shfl_xor(qv[j], 16, 64); qv[j] += __shfl_xor(qv[j], 32, 64);
    }
    __shared__ float ls[4][64], lq[4][64];
    if (g == 0) {
#pragma unroll
        for (int j = 0; j < 4; j++) { ls[wid][s + 16 * j] = sv[j]; lq[wid][s + 16 * j] = qv[j]; }
    }
    __syncthreads();
    if (wid == 0) {
        float S = ls[0][lane] + ls[1][lane] + ls[2][lane] + ls[3][lane];
        float Q = lq[0][lane] + lq[1][lane] + lq[2][lane] + lq[3][lane];
        float* rep = statsRep + (blockIdx.x & (NREP - 1)) * 128;
        atomicAdd(&rep[lane], S);
        atomicAdd(&rep[64 + lane], Q);
    }
}

// ---------------- GEMM 64x64 (replica-fold BN + relu fused; f16 in, f16 out) ----------

#define G64_ROWS 128
__global__ void gemm64_kernel(const _Float16* __restrict__ hin, const float* __restrict__ W,
                              const float* __restrict__ statsRep, const float* __restrict__ gamma,
                              const float* __restrict__ beta, const float* __restrict__ dis,
                              _Float16* __restrict__ hout) {
    __shared__ float Ws[HID * HID];              // [k][f], f contiguous
    __shared__ float hs[G64_ROWS][HID + 2];      // +2 pad: conflict-free float2 reads
    __shared__ float scb[64], shb[64];
    int t = threadIdx.x;
    int fg = t & 15;
    int rg = t >> 4;
    int base = blockIdx.x * G64_ROWS;

    if (t < 64) bn_coef_rep(statsRep, gamma, beta, t, scb[t], shb[t]);
    {
        const float4* W4 = (const float4*)W;
        float4* Ws4 = (float4*)Ws;
        for (int i = t; i < HID * HID / 4; i += 256) Ws4[i] = W4[i];
    }
    __syncthreads();
    {
        const half4* hin4 = (const half4*)hin;
        for (int i = t; i < G64_ROWS * 16; i += 256) {
            int r = i >> 4, c = i & 15;
            int n = base + r;
            float4 v = make_float4(0.f, 0.f, 0.f, 0.f);
            if (n < N_NODES) {
                half4 h = hin4[n * 16 + c];
                v.x = fmaxf((float)h.x * scb[c * 4 + 0] + shb[c * 4 + 0], 0.f);
                v.y = fmaxf((float)h.y * scb[c * 4 + 1] + shb[c * 4 + 1], 0.f);
                v.z = fmaxf((float)h.z * scb[c * 4 + 2] + shb[c * 4 + 2], 0.f);
                v.w = fmaxf((float)h.w * scb[c * 4 + 3] + shb[c * 4 + 3], 0.f);
            }
            hs[r][c * 4 + 0] = v.x;
            hs[r][c * 4 + 1] = v.y;
            hs[r][c * 4 + 2] = v.z;
            hs[r][c * 4 + 3] = v.w;
        }
    }
    __syncthreads();

    float4 acc[8];
#pragma unroll
    for (int r = 0; r < 8; r++) acc[r] = make_float4(0.f, 0.f, 0.f, 0.f);
    const float4* Ws4 = (const float4*)Ws;
    for (int k = 0; k < HID; k += 2) {
        float4 wk0 = Ws4[k * 16 + fg];
        float4 wk1 = Ws4[(k + 1) * 16 + fg];
#pragma unroll
        for (int r = 0; r < 8; r++) {
            float2 h2 = *(const float2*)&hs[rg * 8 + r][k];
            acc[r].x += h2.x * wk0.x + h2.y * wk1.x;
            acc[r].y += h2.x * wk0.y + h2.y * wk1.y;
            acc[r].z += h2.x * wk0.z + h2.y * wk1.z;
            acc[r].w += h2.x * wk0.w + h2.y * wk1.w;
        }
    }
    half4* hout4 = (half4*)hout;
#pragma unroll
    for (int r = 0; r < 8; r++) {
        int n = base + rg * 8 + r;
        if (n < N_NODES) {
            float dsc = dis[n];
            half4 o;
            o.x = (_Float16)(acc[r].x * dsc);
            o.y = (_Float16)(acc[r].y * dsc);
            o.z = (_Float16)(acc[r].z * dsc);
            o.w = (_Float16)(acc[r].w * dsc);
            hout4[n * 16 + fg] = o;
        }
    }
}

// ---------------- Aggregation 64-dim: 2 nodes/wave (4 slots x 8 half8-cols), f16 y -----

__global__ void aggregate_kernel(const half8* __restrict__ hwh, const int* __restrict__ csrOff,
                                 const int* __restrict__ csrSrc, const float* __restrict__ dis,
                                 const float* __restrict__ bias, half8* __restrict__ y8,
                                 float* __restrict__ statsRep) {
    const int lane = threadIdx.x & 63;
    const int wid = threadIdx.x >> 6;
    const int g = lane >> 5;  // node subgroup 0..1
    const int s = lane & 31;
    const int c = s & 7;      // half8 column within the 64-half row
    const int o = s >> 3;     // edge slot 0..3
    const int wave = blockIdx.x * 4 + wid;
    const int nwaves = gridDim.x * 4;

    const float4 bv0 = ((const float4*)bias)[c * 2];
    const float4 bv1 = ((const float4*)bias)[c * 2 + 1];
    float sa[8], qa[8];
#pragma unroll
    for (int j = 0; j < 8; j++) { sa[j] = 0.f; qa[j] = 0.f; }

    for (int n0 = wave * 2; n0 < N_NODES; n0 += nwaves * 2) {
        int n = n0 + g;
        bool vn = (n < N_NODES);
        int beg = 0, end = 0;
        if (vn) { beg = csrOff[n]; end = csrOff[n + 1]; }
        float acc[8];
#pragma unroll
        for (int j = 0; j < 8; j++) acc[j] = 0.f;
        int e = beg + o;
        int i0 = (e < end) ? csrSrc[e] : N_NODES;
        int i1 = (e + 4 < end) ? csrSrc[e + 4] : N_NODES;
        while (e < end) {
            int j0 = i0, j1 = i1;
            e += 8;
            i0 = (e < end) ? csrSrc[e] : N_NODES;
            i1 = (e + 4 < end) ? csrSrc[e + 4] : N_NODES;
            half8 h0 = hwh[(size_t)j0 * 8 + c];
            half8 h1 = hwh[(size_t)j1 * 8 + c];
#pragma unroll
            for (int j = 0; j < 8; j++) acc[j] += (float)h0[j] + (float)h1[j];
        }
#pragma unroll
        for (int j = 0; j < 8; j++) {
            acc[j] += __shfl_xor(acc[j], 8, 64);
            acc[j] += __shfl_xor(acc[j], 16, 64);
        }
        if (o == 0 && vn) {
            float d = dis[n];
            float val[8];
            val[0] = acc[0] * d + bv0.x; val[1] = acc[1] * d + bv0.y;
            val[2] = acc[2] * d + bv0.z; val[3] = acc[3] * d + bv0.w;
            val[4] = acc[4] * d + bv1.x; val[5] = acc[5] * d + bv1.y;
            val[6] = acc[6] * d + bv1.z; val[7] = acc[7] * d + bv1.w;
            half8 ov;
#pragma unroll
            for (int j = 0; j < 8; j++) ov[j] = (_Float16)val[j];
            y8[(size_t)n * 8 + c] = ov;
#pragma unroll
            for (int j = 0; j < 8; j++) { sa[j] += val[j]; qa[j] += val[j] * val[j]; }
        }
    }
#pragma unroll
    for (int j = 0; j < 8; j++) {
        sa[j] += __shfl_xor(sa[j], 32, 64);
        qa[j] += __shfl_xor(qa[j], 32, 64);
    }
    __shared__ float ls[4][64], lq[4][64];
    ls[wid][lane] = 0.f;
    lq[wid][lane] = 0.f;
    if (lane < 8) {  // o==0 && g==0; c == lane
#pragma unroll
        for (int j = 0; j < 8; j++) { ls[wid][lane * 8 + j] = sa[j]; lq[wid][lane * 8 + j] = qa[j]; }
    }
    __syncthreads();
    if (wid == 0) {
        float S = ls[0][lane] + ls[1][lane] + ls[2][lane] + ls[3][lane];
        float Q = lq[0][lane] + lq[1][lane] + lq[2][lane] + lq[3][lane];
        float* rep = statsRep + (blockIdx.x & (NREP - 1)) * 128;
        atomicAdd(&rep[lane], S);
        atomicAdd(&rep[64 + lane], Q);
    }
}

// ---------------- Pool (replica-fold BN + relu fused) + head ----------------

#define POOL_CHUNK 256
__global__ void pool_kernel(const _Float16* __restrict__ y, const int* __restrict__ batch,
                            const float* __restrict__ statsRep, const float* __restrict__ gamma,
                            const float* __restrict__ beta, float* __restrict__ pool,
                            float* __restrict__ cnt) {
    __shared__ float scs[64], shs[64];
    int t = threadIdx.x;
    int f = t & 63;
    int nl = t >> 6;
    if (t < 64) bn_coef_rep(statsRep, gamma, beta, t, scs[t], shs[t]);
    __syncthreads();
    float sc = scs[f], sh = shs[f];
    int base = blockIdx.x * POOL_CHUNK;
    int endn = min(base + POOL_CHUNK, N_NODES);
    int g_cur = -1;
    float acc = 0.f;
    float c_acc = 0.f;
    for (int n = base + nl; n < endn; n += 4) {
        int g = batch[n];
        float v = fmaxf((float)y[(size_t)n * HID + f] * sc + sh, 0.f);
        if (g != g_cur) {
            if (g_cur >= 0) {
                atomicAdd(&pool[g_cur * HID + f], acc);
                if (f == 0) atomicAdd(&cnt[g_cur], c_acc);
            }
            g_cur = g;
            acc = 0.f;
            c_acc = 0.f;
        }
        acc += v;
        c_acc += 1.f;
    }
    if (g_cur >= 0) {
        atomicAdd(&pool[g_cur * HID + f], acc);
        if (f == 0) atomicAdd(&cnt[g_cur], c_acc);
    }
}

__global__ void head_kernel(const float* __restrict__ pool, const float* __restrict__ cnt,
                            const float* __restrict__ Wc1, const float* __restrict__ bc1,
                            const float* __restrict__ Wc2, const float* __restrict__ bc2,
                            float* __restrict__ out) {
    int g = blockIdx.x;
    int f = threadIdx.x;  // 64 threads
    __shared__ float p[64], z[64];
    float c = fmaxf(cnt[g], 1.0f);
    p[f] = pool[g * HID + f] / c;
    __syncthreads();
    float acc = bc1[f];
    for (int k = 0; k < 64; k++) acc += p[k] * Wc1[k * 64 + f];
    z[f] = fmaxf(acc, 0.f);
    __syncthreads();
    if (f < 2) {
        float o = bc2[f];
        for (int k = 0; k < 64; k++) o += z[k] * Wc2[k * 2 + f];
        out[g * 2 + f] = o;
    }
}

// ---------------- launch ----------------

extern "C" void kernel_launch(void* const* d_in, const int* in_sizes, int n_in,
                              void* d_out, int out_size, void* d_ws, size_t ws_size,
                              hipStream_t stream) {
    const float* x      = (const float*)d_in[0];
    const int*   ei     = (const int*)d_in[1];
    const int*   batch  = (const int*)d_in[2];
    const float* bn_in_g = (const float*)d_in[3];
    const float* bn_in_b = (const float*)d_in[4];
    const float* W0 = (const float*)d_in[5];
    const float* b0 = (const float*)d_in[6];
    const float* g0 = (const float*)d_in[7];
    const float* be0 = (const float*)d_in[8];
    const float* W1 = (const float*)d_in[9];
    const float* b1 = (const float*)d_in[10];
    const float* g1 = (const float*)d_in[11];
    const float* be1 = (const float*)d_in[12];
    const float* W2 = (const float*)d_in[13];
    const float* b2 = (const float*)d_in[14];
    const float* g2 = (const float*)d_in[15];
    const float* be2 = (const float*)d_in[16];
    const float* Wc1 = (const float*)d_in[17];
    const float* bc1 = (const float*)d_in[18];
    const float* Wc2 = (const float*)d_in[19];
    const float* bc2 = (const float*)d_in[20];
    float* out = (float*)d_out;

    char* w = (char*)d_ws;
    size_t off = 0;
    auto take = [&](size_t bytes) {
        size_t r = off;
        off += (bytes + 255) & ~(size_t)255;
        return r;
    };
    // ---- zero region (one memset) ----
    float* stats    = (float*)(w + take(256 * 4));             // s0: [sums 64][sumsq 64]
    float* statsRep = (float*)(w + take(3 * NREP * 128 * 4));  // replicated accumulators
    float* pool     = (float*)(w + take((size_t)N_GRAPHS * HID * 4));
    float* cnt      = (float*)(w + take((size_t)N_GRAPHS * 4));
    int* bucketCnt  = (int*)(w + take((size_t)NB_BUCKETS * 4));
    size_t zero_end = off;
    // ---- rest ----
    float* dis    = (float*)(w + take((size_t)N_NODES * 4));
    int* csrOff   = (int*)(w + take((size_t)(N_NODES + 1) * 4));
    int* csrSrc   = (int*)(w + take((size_t)(CSR_LEN + 64) * 4));
    _Float16* hwBuf = (_Float16*)(w + take((size_t)(N_NODES + 1) * HID * 2));  // f16 msgs +dummy
    _Float16* yBuf  = (_Float16*)(w + take((size_t)N_NODES * HID * 2));        // f16 activations
    _Float16* msgBuf = (_Float16*)(w + take((size_t)(N_NODES + 1) * IN_DIM * 2));  // f16 16-dim
    int* regions  = (int*)hwBuf;   // alias: consumed by build_kernel before gemm64 writes
    (void)ws_size; (void)n_in; (void)in_sizes; (void)out_size;

    hipMemsetAsync(w, 0, zero_end, stream);

    const int nbBin   = (N_EDGES + BIN_TILE - 1) / BIN_TILE;  // 293
    const int nbG64   = (N_NODES + G64_ROWS - 1) / G64_ROWS;
    const int nbAgg16 = (N_NODES + 16 * 4 - 1) / (16 * 4);  // 4 waves x 4 nodes per block
    const int nbAgg64 = (N_NODES + 8 * 4 - 1) / (8 * 4);    // 4 waves x 2 nodes per block

    float* s0 = stats;
    float* rep1 = statsRep + 0 * NREP * 128;
    float* rep2 = statsRep + 1 * NREP * 128;
    float* rep3 = statsRep + 2 * NREP * 128;

    // CSR build (bucketed; self-loops folded in) + input BN stats (merged into bin launch)
    bin_stats_kernel<<<nbBin + STATS_BLKS, 256, 0, stream>>>(ei, bucketCnt, regions, x, s0,
                                                             s0 + 64, hwBuf, nbBin);
    // build CSR + fused premsg tail (BN coefs + dis in-register)
    build_kernel<<<NB_BUCKETS, 256, 0, stream>>>(regions, bucketCnt, csrOff, csrSrc, dis, x,
                                                 s0, s0 + 64, bn_in_g, bn_in_b,
                                                 (half4*)msgBuf);

    // layer 0: fused 16-dim aggregate + W0 GEMM (f16 y out)
    agg16_gemm0_kernel<<<nbAgg16, 256, 0, stream>>>((const half4*)msgBuf, csrOff, csrSrc, dis,
                                                    W0, b0, yBuf, rep1);

    // layer 1 (gemm folds rep1 reduce + BN)
    gemm64_kernel<<<nbG64, 256, 0, stream>>>(yBuf, W1, rep1, g0, be0, dis, hwBuf);
    aggregate_kernel<<<nbAgg64, 256, 0, stream>>>((const half8*)hwBuf, csrOff, csrSrc, dis, b1,
                                                  (half8*)yBuf, rep2);
    // layer 2
    gemm64_kernel<<<nbG64, 256, 0, stream>>>(yBuf, W2, rep2, g1, be1, dis, hwBuf);
    aggregate_kernel<<<nbAgg64, 256, 0, stream>>>((const half8*)hwBuf, csrOff, csrSrc, dis, b2,
                                                  (half8*)yBuf, rep3);

    // pool (folds rep3 reduce + BN) + head
    const int nbPool = (N_NODES + POOL_CHUNK - 1) / POOL_CHUNK;
    pool_kernel<<<nbPool, 256, 0, stream>>>(yBuf, batch, rep3, g2, be2, pool, cnt);
    head_kernel<<<N_GRAPHS, 64, 0, stream>>>(pool, cnt, Wc1, bc1, Wc2, bc2, out);
}